// Round 4
// baseline (213.054 us; speedup 1.0000x reference)
//
#include <hip/hip_runtime.h>
#include <stdint.h>
#include <math.h>

#define SLEN 2048
#define EPT 16               // elements per lane: half a row per wave
#define NTHREADS 128         // 2 waves = 1 row per block
#define CPW 4                // chunks (of 256 el) per wave; row = 8 chunks
#define TOKENS_PER_OUT 8388608   // 1024*4*2048

// ---------- Threefry-2x32, 20 rounds, matches jax._src.prng ----------
__host__ __device__ __forceinline__ void tf2x32(uint32_t k0, uint32_t k1,
                                                uint32_t x0, uint32_t x1,
                                                uint32_t &o0, uint32_t &o1) {
  uint32_t ks2 = 0x1BD11BDAu ^ k0 ^ k1;
  x0 += k0; x1 += k1;
#define TFR(r) { x0 += x1; x1 = (x1 << (r)) | (x1 >> (32 - (r))); x1 ^= x0; }
  TFR(13) TFR(15) TFR(26) TFR(6)
  x0 += k1;  x1 += ks2 + 1u;
  TFR(17) TFR(29) TFR(16) TFR(24)
  x0 += ks2; x1 += k0 + 2u;
  TFR(13) TFR(15) TFR(26) TFR(6)
  x0 += k0;  x1 += k1 + 3u;
  TFR(17) TFR(29) TFR(16) TFR(24)
  x0 += k1;  x1 += ks2 + 4u;
  TFR(13) TFR(15) TFR(26) TFR(6)
  x0 += ks2; x1 += k0 + 5u;
#undef TFR
  o0 = x0; o1 = x1;
}

// 4 independent threefry streams; sched_barrier after each round keeps the
// 4-wide interleave intact through the machine scheduler.
__device__ __forceinline__ void tf4_bits(uint32_t k0, uint32_t k1,
                                         uint32_t cbase, uint32_t bits[4]) {
  const uint32_t ks2 = 0x1BD11BDAu ^ k0 ^ k1;
  uint32_t x0[4], x1[4];
#pragma unroll
  for (int i = 0; i < 4; ++i) { x0[i] = k0; x1[i] = (cbase + (uint32_t)i) + k1; }
#define TFR4(r)                                                         \
  _Pragma("unroll")                                                     \
  for (int i = 0; i < 4; ++i) {                                         \
    x0[i] += x1[i];                                                     \
    x1[i] = (x1[i] << (r)) | (x1[i] >> (32 - (r)));                     \
    x1[i] ^= x0[i];                                                     \
  }                                                                     \
  __builtin_amdgcn_sched_barrier(0);
#define INJ4(a, b)                                                      \
  _Pragma("unroll")                                                     \
  for (int i = 0; i < 4; ++i) { x0[i] += (a); x1[i] += (b); }
  TFR4(13) TFR4(15) TFR4(26) TFR4(6)
  INJ4(k1, ks2 + 1u)
  TFR4(17) TFR4(29) TFR4(16) TFR4(24)
  INJ4(ks2, k0 + 2u)
  TFR4(13) TFR4(15) TFR4(26) TFR4(6)
  INJ4(k0, k1 + 3u)
  TFR4(17) TFR4(29) TFR4(16) TFR4(24)
  INJ4(k1, ks2 + 4u)
  TFR4(13) TFR4(15) TFR4(26) TFR4(6)
  INJ4(ks2, k0 + 5u)
#undef TFR4
#undef INJ4
#pragma unroll
  for (int i = 0; i < 4; ++i) bits[i] = x0[i] ^ x1[i];
}

__device__ __forceinline__ float u01_from_bits(uint32_t bits) {
  return __uint_as_float((bits >> 9) | 0x3F800000u) - 1.0f;
}

#define SBAR() __builtin_amdgcn_sched_barrier(0)

// 8 correctly-rounded-quality f32 logs (positive normal f32 inputs), staged
// 8-wide with hard sched barriers so dependent f64 ops sit ~8 instrs apart.
// Bit-identical to the verified scalar math:
//   x = 2^e * m, m in [sqrt2/2, sqrt2), r = (m-1)*rcp(m+1) w/ 1 Newton,
//   log = e*ln2 + 2r*(1 + t/3 + .. + t^6/13).
__device__ __forceinline__ void log8_cr(const float x[8], float out[8]) {
#pragma clang fp contract(off)
  double m[8]; int e[8];
#pragma unroll
  for (int i = 0; i < 8; ++i) {
    uint32_t xb   = __float_as_uint(x[i]);
    uint32_t mant = xb & 0x7FFFFFu;
    int      ee   = (int)(xb >> 23) - 127;
    bool     big  = mant > 0x3504F3u;          // m > sqrt(2)
    e[i] = ee + (big ? 1 : 0);
    uint32_t hi = (big ? 0x3FE00000u : 0x3FF00000u) | (mant >> 3);
    uint32_t lo = mant << 29;
    m[i] = __longlong_as_double(((long long)hi << 32) | (long long)lo);
  }
  SBAR();
  double mp1[8];
#pragma unroll
  for (int i = 0; i < 8; ++i) mp1[i] = m[i] + 1.0;
  SBAR();
  double y[8];
#pragma unroll
  for (int i = 0; i < 8; ++i) y[i] = __builtin_amdgcn_rcp(mp1[i]);
  SBAR();
#pragma unroll
  for (int i = 0; i < 8; ++i) y[i] = fma(fma(-mp1[i], y[i], 1.0), y[i], y[i]);
  SBAR();
  double r[8];
#pragma unroll
  for (int i = 0; i < 8; ++i) r[i] = (m[i] - 1.0) * y[i];
  SBAR();
  double t[8];
#pragma unroll
  for (int i = 0; i < 8; ++i) t[i] = r[i] * r[i];
  SBAR();
  double p[8];
#pragma unroll
  for (int i = 0; i < 8; ++i) p[i] = fma(0.07692307692307693, t[i], 0.09090909090909091);
  SBAR();
#pragma unroll
  for (int i = 0; i < 8; ++i) p[i] = fma(p[i], t[i], 0.1111111111111111);
  SBAR();
#pragma unroll
  for (int i = 0; i < 8; ++i) p[i] = fma(p[i], t[i], 0.14285714285714285);
  SBAR();
#pragma unroll
  for (int i = 0; i < 8; ++i) p[i] = fma(p[i], t[i], 0.2);
  SBAR();
#pragma unroll
  for (int i = 0; i < 8; ++i) p[i] = fma(p[i], t[i], 0.3333333333333333);
  SBAR();
#pragma unroll
  for (int i = 0; i < 8; ++i) p[i] = fma(p[i], t[i], 1.0);
  SBAR();
#pragma unroll
  for (int i = 0; i < 8; ++i) r[i] = r[i] + r[i];       // 2r (exact)
  SBAR();
#pragma unroll
  for (int i = 0; i < 8; ++i) p[i] = r[i] * p[i];       // 2r*q
  SBAR();
#pragma unroll
  for (int i = 0; i < 8; ++i)
    out[i] = (float)fma((double)e[i], 0.6931471805599453, p[i]);
}

// scalar CR log (erfinv path only; same math, unstaged)
__device__ __forceinline__ float log_cr(float x) {
#pragma clang fp contract(off)
  uint32_t xb   = __float_as_uint(x);
  uint32_t mant = xb & 0x7FFFFFu;
  int      e    = (int)(xb >> 23) - 127;
  bool     big  = mant > 0x3504F3u;
  e += big ? 1 : 0;
  uint32_t hi = (big ? 0x3FE00000u : 0x3FF00000u) | (mant >> 3);
  double m = __longlong_as_double(((long long)hi << 32) | (long long)(mant << 29));
  double mp1 = m + 1.0;
  double y = __builtin_amdgcn_rcp(mp1);
  y = fma(fma(-mp1, y, 1.0), y, y);
  double r = (m - 1.0) * y;
  double t = r * r;
  double p = fma(0.07692307692307693, t, 0.09090909090909091);
  p = fma(p, t, 0.1111111111111111);
  p = fma(p, t, 0.14285714285714285);
  p = fma(p, t, 0.2);
  p = fma(p, t, 0.3333333333333333);
  p = fma(p, t, 1.0);
  return (float)fma((double)e, 0.6931471805599453, (r + r) * p);
}

// XLA ErfInv f32 expander (Giles poly), log1p per ElementalIrEmitter::EmitLog1p
__device__ float erfinv_xla(float x) {
#pragma clang fp contract(off)
  float x2  = x * x;
  float nx2 = -x2;
  float l1p;
  if (fabsf(nx2) < 1e-4f) {
    l1p = (-0.5f * nx2 + 1.0f) * nx2;
  } else {
    l1p = log_cr(1.0f + nx2);
  }
  float w = -l1p;
  float p;
  if (w < 5.0f) {
    float ww = w - 2.5f;
    p = 2.81022636e-08f;
    p = p * ww + 3.43273939e-07f;
    p = p * ww + -3.5233877e-06f;
    p = p * ww + -4.39150654e-06f;
    p = p * ww + 0.00021858087f;
    p = p * ww + -0.00125372503f;
    p = p * ww + -0.00417768164f;
    p = p * ww + 0.246640727f;
    p = p * ww + 1.50140941f;
  } else {
    float ww = sqrtf(w) - 3.0f;
    p = -0.000200214257f;
    p = p * ww + 0.000100950558f;
    p = p * ww + 0.00134934322f;
    p = p * ww + -0.00367342844f;
    p = p * ww + 0.00573950773f;
    p = p * ww + -0.0076224613f;
    p = p * ww + 0.00943887047f;
    p = p * ww + 1.00167406f;
    p = p * ww + 2.83297682f;
  }
  return p * x;
}

// R4: 2 waves per row (16 el/lane), 128-thread blocks, grid=4096.
// R3 showed the VALU issue floor is ~40us in every structure; the other
// ~38us is stall time with only 4 waves/SIMD (grid 1024 = whole grid
// resident in one generation, homogeneous waves convoy through the
// DS-latency select phase together). Doubling waves to 32/CU (16 blocks/CU)
// halves the un-hidden stall fraction. Cost: hist is block-shared again
// (~9 __syncthreads), but barriers couple only 2 same-length waves, and
// 16 independent blocks/CU provide scheduler diversity. Bin-selection scan
// is computed redundantly per wave (identical inputs -> identical T/need).
// Ping-pong hist keeps it at 2 barriers/pass; each wave clears its half.
__global__ __launch_bounds__(NTHREADS, 8)
void gumbel_topk_mask(const float* __restrict__ wfull,   // (B,C,2S) f32
                      const int*   __restrict__ attn,    // (B,C,S) i32
                      const int*   __restrict__ ids,     // (B,C,S) i32
                      int* __restrict__ out,             // 3x(B,C,S) i32 concat
                      uint32_t kg0, uint32_t kg1, uint32_t kn0, uint32_t kn1) {
#pragma clang fp contract(off)
  const int t    = threadIdx.x;
  const int lane = t & 63;
  const int wid  = t >> 6;            // 0 or 1: which half-row
  const int row  = blockIdx.x;

  __shared__ __align__(16) uint32_t hist[2][256];
  __shared__ uint32_t wsum[2];
  __shared__ uint32_t wtot[2];

  const size_t rbase = (size_t)row * SLEN;
  const size_t wbase = (size_t)row * (2 * SLEN);

  // zero my half of hist buffer 0 (buffer 1 gets cleared in pass 3's window)
  ((uint2*)hist[0])[64 * wid + lane] = make_uint2(0u, 0u);

  const int4*   av4 = (const int4*)(attn + rbase);
  const float4* wv4 = (const float4*)(wfull + wbase);
  const int4*   iv4 = (const int4*)(ids + rbase);

  // ---- attention loads (coalesced, consumed immediately) ----
  int psum = 0;
#pragma unroll
  for (int j = 0; j < CPW; ++j) {
    int4 a = av4[64 * (CPW * wid + j) + lane];
    psum += a.x + a.y + a.z + a.w;
  }

  // ---- frac (redundant per wave; long f64 chain hides load latency) ----
  uint32_t no0, no1;
  tf2x32(kn0, kn1, 0u, (uint32_t)row, no0, no1);
  float f0  = u01_from_bits(no0 ^ no1);
  float lo  = __uint_as_float(0xBF7FFFFFu);        // nextafter(-1,0)
  float u2  = fmaxf(lo, f0 * 2.0f + lo);           // (1-lo) rounds to 2.0f
  float z   = erfinv_xla(u2);
  float nrm = 1.4142135623730951f * z;
  float frac = 0.15f + 0.0375f * nrm;

  // ---- half-row attention sum -> LDS ----
#pragma unroll
  for (int off = 32; off; off >>= 1) psum += __shfl_down(psum, off, 64);
  if (lane == 0) wsum[wid] = (uint32_t)psum;

  // ---- key pipeline: 2 chunk-pairs x 8 elements (forced-ILP) ----
  // local chunk lj (0..3) = global chunk CPW*wid + lj; element 256*g + 4*lane + e.
  // mloc[4*lj + e] in index order within my half.
  uint32_t mloc[EPT];
#pragma unroll
  for (int c = 0; c < 2; ++c) {
    const int g0 = CPW * wid + 2 * c;
    float4 wa = wv4[64 * g0 + lane];
    float4 wb = wv4[64 * (g0 + 1) + lane];
    uint32_t bits[8];
    tf4_bits(kg0, kg1, (uint32_t)(rbase + 256 * g0 + 4 * lane), bits + 0);
    tf4_bits(kg0, kg1, (uint32_t)(rbase + 256 * (g0 + 1) + 4 * lane), bits + 4);
    SBAR();
    float wl[8] = {wa.x, wa.y, wa.z, wa.w, wb.x, wb.y, wb.z, wb.w};
    float uu[8];
#pragma unroll
    for (int e = 0; e < 8; ++e) {
      float f = u01_from_bits(bits[e]);
      uu[e] = fmaxf(1.17549435e-38f, f * 1.0f + 1.17549435e-38f);
    }
    SBAR();
    float l1[8];
    log8_cr(uu, l1);                       // log u
    float wm[8];
#pragma unroll
    for (int e = 0; e < 8; ++e) wm[e] = fmaxf(wl[e], 1e-30f);
    float lw[8];
    log8_cr(wm, lw);                       // log w
    float nl1[8];
#pragma unroll
    for (int e = 0; e < 8; ++e) nl1[e] = -l1[e];
    float l2[8];
    log8_cr(nl1, l2);                      // log(-log u); gumbel = -l2
    SBAR();
#pragma unroll
    for (int e = 0; e < 8; ++e) {
      float key = (wl[e] > 0.0f) ? (lw[e] + (-l2[e])) : -__builtin_inff();
      uint32_t kb = __float_as_uint(key);
      mloc[8 * c + e] = (kb & 0x80000000u) ? ~kb : (kb | 0x80000000u);  // monotone
    }
  }

  // ids loads: issue now, consumed in epilogue (hidden under the select)
  int4 idsv[CPW];
#pragma unroll
  for (int j = 0; j < CPW; ++j) idsv[j] = iv4[64 * (CPW * wid + j) + lane];

  __syncthreads();                 // hist[0] zeros + wsum visible block-wide
  int asum = (int)(wsum[0] + wsum[1]);
  int kk = (int)floorf((float)asum * frac);

  // ---- block-shared radix-select of the k-th largest key ----
  uint32_t T, r;
  if (kk <= 0)          { T = 0xFFFFFFFFu; r = 0u; }             // mask nothing
  else if (kk >= SLEN)  { T = 0u;          r = (uint32_t)SLEN; } // mask all
  else {
    T = 0u;
    uint32_t need = (uint32_t)kk;
#pragma unroll
    for (int e = 0; e < EPT; ++e)
      atomicAdd(&hist[0][mloc[e] >> 24], 1u);
    int cur = 0;
    for (int p = 3; ; --p) {
      __syncthreads();                                   // pass-p atomics done
      uint4 hq = ((const uint4*)hist[cur])[lane];        // bins 4*lane..+3
      ((uint2*)hist[cur ^ 1])[64 * wid + lane] = make_uint2(0u, 0u);  // clear other
      uint32_t gs  = hq.x + hq.y + hq.z + hq.w;
      uint32_t sfx = gs;                                 // inclusive suffix sum
#pragma unroll
      for (int off = 1; off < 64; off <<= 1) {
        uint32_t n = __shfl_down(sfx, off, 64);
        if (lane + off < 64) sfx += n;
      }
      uint32_t Gex = sfx - gs;                           // sum over lanes > me
      uint32_t S3 = Gex;
      uint32_t S2 = S3 + hq.w;
      uint32_t S1 = S2 + hq.z;
      uint32_t S0 = S1 + hq.y;
      uint32_t hh[4] = {hq.x, hq.y, hq.z, hq.w};
      uint32_t SS[4] = {S0, S1, S2, S3};
      int haswin = 0; uint32_t binv = 0u, remv = 0u; int donev = 0;
#pragma unroll
      for (int i = 0; i < 4; ++i) {
        if (hh[i] && SS[i] < need && need <= SS[i] + hh[i]) {   // unique winner
          haswin = 1;
          binv = (uint32_t)(4 * lane + i);
          remv = need - SS[i];
          donev = (remv == hh[i]) ? 1 : 0;   // whole bin taken: low bytes stay 0
        }
      }
      unsigned long long wmask = __ballot(haswin);
      int src = (int)(__ffsll((unsigned long long)wmask) - 1);
      uint32_t bin = (uint32_t)__shfl((int)binv, src, 64);
      uint32_t rem = (uint32_t)__shfl((int)remv, src, 64);
      int     done = __shfl(donev, src, 64);
      T |= bin << (8 * p);
      need = rem;
      if (done || p == 0) { r = rem; break; }            // uniform block-wide
      __syncthreads();                                   // reads + clears done
      const int sh = 8 * p;
#pragma unroll
      for (int e = 0; e < EPT; ++e) {
        uint32_t m = mloc[e];
        if ((m >> sh) == (T >> sh))
          atomicAdd(&hist[cur ^ 1][(m >> (sh - 8)) & 255u], 1u);
      }
      cur ^= 1;
    }
  }

  // ---- stable tie-break in INDEX order (within wave, then across waves) ----
  uint32_t cnt[CPW];
#pragma unroll
  for (int j = 0; j < CPW; ++j) {
    uint32_t c = 0;
#pragma unroll
    for (int e = 0; e < 4; ++e) c += (mloc[4 * j + e] == T) ? 1u : 0u;
    cnt[j] = c;
  }
  uint32_t incl[2];
#pragma unroll
  for (int q = 0; q < 2; ++q) incl[q] = cnt[2 * q] | (cnt[2 * q + 1] << 16);
#pragma unroll
  for (int off = 1; off < 64; off <<= 1) {
#pragma unroll
    for (int q = 0; q < 2; ++q) {
      uint32_t n = __shfl_up(incl[q], off, 64);
      if (lane >= off) incl[q] += n;
    }
  }
  uint32_t Spre[CPW], tot[CPW];
#pragma unroll
  for (int q = 0; q < 2; ++q) {
    uint32_t t63 = (uint32_t)__shfl((int)incl[q], 63, 64);
    tot[2 * q]      = t63 & 0xFFFFu;
    tot[2 * q + 1]  = t63 >> 16;
    Spre[2 * q]     = (incl[q] & 0xFFFFu) - cnt[2 * q];
    Spre[2 * q + 1] = (incl[q] >> 16)     - cnt[2 * q + 1];
  }
  if (lane == 0) wtot[wid] = tot[0] + tot[1] + tot[2] + tot[3];
  __syncthreads();
  uint32_t C = wid ? wtot[0] : 0u;   // eq-count in the other wave's earlier half

  // ---- epilogue: masked writes (coalesced) ----
  int4* po = (int4*)(out + rbase);
  int4* pm = (int4*)(out + TOKENS_PER_OUT + rbase);
  int4* pl = (int4*)(out + 2 * TOKENS_PER_OUT + rbase);
#pragma unroll
  for (int j = 0; j < CPW; ++j) {
    uint32_t excl = C + Spre[j];
    int4 iv = idsv[j];
    int idv[4] = {iv.x, iv.y, iv.z, iv.w};
    int oid[4], omk[4], olb[4];
#pragma unroll
    for (int e = 0; e < 4; ++e) {
      uint32_t m = mloc[4 * j + e];
      bool eq  = (m == T);
      bool msk = (m > T) || (eq && (excl < r));
      excl += eq ? 1u : 0u;
      oid[e] = msk ? 103 : idv[e];      // MASK_ID
      omk[e] = msk ? 1 : 0;
      olb[e] = msk ? -1 : 0;
    }
    const int gi = 64 * (CPW * wid + j) + lane;
    po[gi] = make_int4(oid[0], oid[1], oid[2], oid[3]);
    pm[gi] = make_int4(omk[0], omk[1], omk[2], omk[3]);
    pl[gi] = make_int4(olb[0], olb[1], olb[2], olb[3]);
    C += tot[j];
  }
}

extern "C" void kernel_launch(void* const* d_in, const int* in_sizes, int n_in,
                              void* d_out, int out_size, void* d_ws, size_t ws_size,
                              hipStream_t stream) {
  (void)n_in; (void)d_ws; (void)ws_size; (void)out_size;
  const float* wfull = (const float*)d_in[0];   // my_attention_mask (B,C,2S)
  const int*   attn  = (const int*)d_in[1];     // attention_mask    (B,C,S)
  const int*   ids   = (const int*)d_in[2];     // input_ids         (B,C,S)
  int* out = (int*)d_out;

  // jax.random.key(42) -> (0,42); partitionable split: kg=enc(key,(0,0)), kn=enc(key,(0,1))
  uint32_t kg0, kg1, kn0, kn1, o0, o1;
  tf2x32(0u, 42u, 0u, 0u, o0, o1); kg0 = o0; kg1 = o1;
  tf2x32(0u, 42u, 0u, 1u, o0, o1); kn0 = o0; kn1 = o1;

  int rows = in_sizes[1] / SLEN;                // 4096
  hipLaunchKernelGGL(gumbel_topk_mask, dim3(rows), dim3(NTHREADS),
                     0, stream, wfull, attn, ids, out, kg0, kg1, kn0, kn1);
}